// Round 17
// baseline (81.015 us; speedup 1.0000x reference)
//
#include <hip/hip_runtime.h>
#include <hip/hip_bf16.h>

typedef __bf16 bf16;
typedef __bf16 bf16x8 __attribute__((ext_vector_type(8)));
typedef __bf16 bf16x4 __attribute__((ext_vector_type(4)));
typedef float  f32x4  __attribute__((ext_vector_type(4)));

#define MFMA16(a,b,c) __builtin_amdgcn_mfma_f32_16x16x32_bf16((a),(b),(c),0,0,0)

__device__ __forceinline__ void gld16(const void* g, void* l) {
    __builtin_amdgcn_global_load_lds(
        (const __attribute__((address_space(1))) void*)g,
        (__attribute__((address_space(3))) void*)l, 16, 0, 0);
}

// Problem sizes: B=512, T=256, C=512, H=64
// ws layout: WTfrag [16 KC][12 nf][64 lane][8] bf16 @ 0  (196,608 bytes)

// ---- kernel 0: build pre-fragmented WT --------------------------------------
__global__ void __launch_bounds__(256) wt_frag_kernel(
        const float* __restrict__ Wq, const float* __restrict__ Wk,
        const float* __restrict__ Wv, bf16* __restrict__ WTfrag) {
    int tid = blockIdx.x * 256 + threadIdx.x;     // 98304 total
    int j  = tid & 7;
    int l  = (tid >> 3) & 63;
    int f  = tid >> 9;            // 0..767 = KC*12 + nf
    int nf = f % 12;
    int KC = f / 12;
    int k   = KC * 32 + (l >> 4) * 8 + j;
    int col = (nf & 3) * 16 + (l & 15);
    const float* W = (nf < 4) ? Wq : ((nf < 8) ? Wk : Wv);
    WTfrag[tid] = (bf16)W[k * 64 + col];
}

// ---- fused kernel: 8-wave small-acc pipelined proj + flash attention --------
// grid 512 (block = batch), 512 threads (8 waves), 1 block/CU (LDS 90112).
// Register model (from R10-R16): per-wave budget = 512/(waves/SIMD). Here
// 8 waves/CU = 2/SIMD -> 256/wave. acc[2][12] = 96 (vs R9's 192) leaves ~160
// arch regs -> in-region stage(k+1)-before-compute(k) double-buffering is
// finally WITHIN budget (the thing that spilled at acc=192 in R10/R11).
// Wave w owns q-frags {w, 15-w} (16-row frags) -> uniform causal work (5
// (qf,kc) pairs/wave), and Q acc feeds attention without cross-wave traffic.
// Phase 1: 16 chunks; x dbuf @0/@32768, wt dbuf @65536/@77824; per chunk:
//   stage(k+1) -> compute(k) -> ONE __syncthreads (compiler vmcnt(0) drain,
//   spill-proof; staging lands under compute).
// Phase 2: K -> @0 (dead x p0), V -> @32768 (dead x p1), swizzled; Q via
//   wave-private Pl transpose @65536+w*2304 (dead wt area).
// Phase 3: causal flash attention (R16 math, 2 frags/wave).
__global__ void __launch_bounds__(512, 1) fused_kernel(
        const float* __restrict__ x, const bf16* __restrict__ WTfrag,
        float* __restrict__ out) {
    extern __shared__ char smem[];

    const int tid = threadIdx.x;
    const int l   = tid & 63;
    const int w   = tid >> 6;            // 0..7
    const int lo  = l & 15;
    const int hi  = l >> 4;
    const int b   = blockIdx.x;
    const int fr0 = w;                   // owned q-frags (16 rows each)
    const int fr1 = 15 - w;
    const char* xb = (const char*)x + (size_t)b * 524288;   // 256 rows * 2048 B
    const char* wb = (const char*)WTfrag;

    // ---------------- phase 1: projection ----------------
    f32x4 acc[2][12];                    // [qi][nf]; 96 regs
    #pragma unroll
    for (int mq = 0; mq < 2; ++mq)
        #pragma unroll
        for (int nf = 0; nf < 12; ++nf)
            acc[mq][nf] = (f32x4){0.f, 0.f, 0.f, 0.f};

    auto stage = [&](int kc) {
        const int p = kc & 1;
        #pragma unroll
        for (int j = 0; j < 4; ++j) {            // x: 2048 16B-units, 4/thread
            const int s   = j * 512 + tid;
            const int row = s >> 3;
            const int uL  = (s & 7) ^ (row & 7); // inverse-swizzle on SOURCE
            gld16(xb + (size_t)row * 2048 + kc * 128 + uL * 16,
                  smem + p * 32768 + s * 16);
        }
        // wt: 768 16B-units (12 KB)
        gld16(wb + kc * 12288 + tid * 16,
              smem + 65536 + p * 12288 + tid * 16);
        if (tid < 256)
            gld16(wb + kc * 12288 + (512 + tid) * 16,
                  smem + 65536 + p * 12288 + (512 + tid) * 16);
    };

    stage(0);
    __syncthreads();                             // chunk 0 landed

    #pragma unroll 1
    for (int kc = 0; kc < 16; ++kc) {
        if (kc < 15) stage(kc + 1);              // lands under compute(kc)
        const char* xlds  = smem + (kc & 1) * 32768;
        const char* wtlds = smem + 65536 + (kc & 1) * 12288;
        bf16x8 a[2];
        #pragma unroll
        for (int mq = 0; mq < 2; ++mq) {
            const int fr  = mq ? fr1 : fr0;
            const int row = fr * 16 + lo;        // row&7 == lo&7
            const int u0  = (hi * 2)     ^ (lo & 7);
            const int u1  = (hi * 2 + 1) ^ (lo & 7);
            f32x4 v0 = *(const f32x4*)(xlds + row * 128 + u0 * 16);
            f32x4 v1 = *(const f32x4*)(xlds + row * 128 + u1 * 16);
            bf16x8 t;
            t[0] = (bf16)v0[0]; t[1] = (bf16)v0[1]; t[2] = (bf16)v0[2]; t[3] = (bf16)v0[3];
            t[4] = (bf16)v1[0]; t[5] = (bf16)v1[1]; t[6] = (bf16)v1[2]; t[7] = (bf16)v1[3];
            a[mq] = t;
        }
        #pragma unroll
        for (int nf = 0; nf < 12; ++nf) {
            bf16x8 bf_ = *(const bf16x8*)(wtlds + nf * 1024 + l * 16);
            acc[0][nf] = MFMA16(a[0], bf_, acc[0][nf]);
            acc[1][nf] = MFMA16(a[1], bf_, acc[1][nf]);
        }
        __syncthreads();     // drains stage(kc+1); frees buf parity kc&1
    }

    // ---------------- phase 2: K,V -> LDS; Q -> regs ----------------
    char* Kb = smem;                     // dead x p0
    char* Vb = smem + 32768;             // dead x p1
    #pragma unroll
    for (int mq = 0; mq < 2; ++mq) {
        const int fr = mq ? fr1 : fr0;
        #pragma unroll
        for (int nf = 4; nf < 8; ++nf) {
            #pragma unroll
            for (int i = 0; i < 4; ++i) {        // K: row varies with i
                bf16 v = (bf16)acc[mq][nf][i];
                const int row = fr * 16 + hi * 4 + i;
                const int col = (nf - 4) * 16 + lo;
                const int u   = col >> 3;
                *(bf16*)(Kb + row * 128 + ((u ^ (row & 7)) << 4) +
                         (col & 7) * 2) = v;
            }
        }
        #pragma unroll
        for (int nf = 8; nf < 12; ++nf) {        // V: one 8B store
            const int h  = (nf - 8) * 16 + lo;
            const int tb = fr * 16 + hi * 4;     // tb&7 in {0,4}
            const int u  = tb >> 3;
            bf16x4 pk;
            pk[0] = (bf16)acc[mq][nf][0]; pk[1] = (bf16)acc[mq][nf][1];
            pk[2] = (bf16)acc[mq][nf][2]; pk[3] = (bf16)acc[mq][nf][3];
            *(bf16x4*)(Vb + h * 512 + ((u ^ (h & 7)) << 4) + (tb & 7) * 2) = pk;
        }
    }

    // Q transpose: wave-private Pl @65536 + w*2304 (dead wt area)
    bf16* Pl = (bf16*)(smem + 65536) + w * 1152;
    bf16x8 qfr[2][2];
    #pragma unroll
    for (int qi = 0; qi < 2; ++qi) {
        #pragma unroll
        for (int nf = 0; nf < 4; ++nf)
            #pragma unroll
            for (int i = 0; i < 4; ++i)
                Pl[(hi * 4 + i) * 72 + nf * 16 + lo] = (bf16)acc[qi][nf][i];
        #pragma unroll
        for (int ks = 0; ks < 2; ++ks)
            qfr[qi][ks] = *(const bf16x8*)(Pl + lo * 72 + ks * 32 + hi * 8);
    }
    __syncthreads();         // K/V scatter visible to all waves

    // ---------------- phase 3: causal flash attention ----------------
    f32x4 o[2][4];
    #pragma unroll
    for (int qi = 0; qi < 2; ++qi)
        #pragma unroll
        for (int mf = 0; mf < 4; ++mf)
            o[qi][mf] = (f32x4){0.f, 0.f, 0.f, 0.f};
    float m2[2]   = {-INFINITY, -INFINITY};
    float lsum[2] = {0.f, 0.f};

    const float SC = 0.125f * 1.44269504088896340736f;  // scale * log2(e)

    #pragma unroll
    for (int kc = 0; kc < 4; ++kc) {
        if (kc > (fr1 >> 2)) continue;           // wave-uniform: all frags done
        bf16x8 vf[4][2];
        #pragma unroll
        for (int mf = 0; mf < 4; ++mf)
            #pragma unroll
            for (int ks = 0; ks < 2; ++ks) {
                const int h = mf * 16 + lo;      // h&7 == lo&7
                const int u = kc * 8 + ks * 4 + hi;
                vf[mf][ks] = *(const bf16x8*)(Vb + h * 512 + ((u ^ (lo & 7)) << 4));
            }

        #pragma unroll
        for (int qi = 0; qi < 2; ++qi) {
            const int f = qi ? fr1 : fr0;
            if (kc > (f >> 2)) continue;         // causal: frag needs this chunk?
            f32x4 s[4];
            #pragma unroll
            for (int kf = 0; kf < 4; ++kf) {
                const int key = kc * 64 + kf * 16 + lo;  // key&7 == lo&7
                bf16x8 k0 = *(const bf16x8*)(Kb + key * 128 + ((hi ^ (lo & 7)) << 4));
                bf16x8 k1 = *(const bf16x8*)(Kb + key * 128 + (((4 + hi) ^ (lo & 7)) << 4));
                f32x4 t = (f32x4){0.f, 0.f, 0.f, 0.f};
                t = MFMA16(k0, qfr[qi][0], t);
                t = MFMA16(k1, qfr[qi][1], t);
                s[kf] = t;
            }
            float mx = -INFINITY;
            const bool diag = (kc == (f >> 2));
            const int qpos  = (f & 3) * 16 + lo; // q position within chunk
            #pragma unroll
            for (int kf = 0; kf < 4; ++kf)
                #pragma unroll
                for (int i = 0; i < 4; ++i) {
                    float v = s[kf][i] * SC;
                    if (diag && (kf * 16 + hi * 4 + i) > qpos) v = -INFINITY;
                    s[kf][i] = v;
                    mx = fmaxf(mx, v);
                }
            mx = fmaxf(mx, __shfl_xor(mx, 16));
            mx = fmaxf(mx, __shfl_xor(mx, 32));
            const float mnew = fmaxf(m2[qi], mx);
            const float rsc  = exp2f(m2[qi] - mnew);
            m2[qi] = mnew;

            float cs = 0.f;
            bf16x4 pk[4];
            #pragma unroll
            for (int kf = 0; kf < 4; ++kf)
                #pragma unroll
                for (int i = 0; i < 4; ++i) {
                    float p = exp2f(s[kf][i] - mnew);
                    cs += p;
                    pk[kf][i] = (bf16)p;
                }
            cs += __shfl_xor(cs, 16);
            cs += __shfl_xor(cs, 32);
            lsum[qi] = lsum[qi] * rsc + cs;

            #pragma unroll
            for (int kf = 0; kf < 4; ++kf)
                *(bf16x4*)(Pl + lo * 72 + kf * 16 + hi * 4) = pk[kf];

            #pragma unroll
            for (int mf = 0; mf < 4; ++mf) {
                o[qi][mf][0] *= rsc; o[qi][mf][1] *= rsc;
                o[qi][mf][2] *= rsc; o[qi][mf][3] *= rsc;
            }
            #pragma unroll
            for (int ks = 0; ks < 2; ++ks) {
                bf16x8 pf = *(const bf16x8*)(Pl + lo * 72 + ks * 32 + hi * 8);
                #pragma unroll
                for (int mf = 0; mf < 4; ++mf)
                    o[qi][mf] = MFMA16(vf[mf][ks], pf, o[qi][mf]);
            }
        }
    }

    // epilogue: out[b][q][h] fp32, coalesced f32x4
    #pragma unroll
    for (int qi = 0; qi < 2; ++qi) {
        const int f = qi ? fr1 : fr0;
        const float inv = 1.0f / lsum[qi];
        const int q = f * 16 + lo;
        #pragma unroll
        for (int mf = 0; mf < 4; ++mf) {
            f32x4 r4;
            r4[0] = o[qi][mf][0] * inv; r4[1] = o[qi][mf][1] * inv;
            r4[2] = o[qi][mf][2] * inv; r4[3] = o[qi][mf][3] * inv;
            *(f32x4*)(out + (b * 256 + q) * 64 + mf * 16 + hi * 4) = r4;
        }
    }
}

// ---- launcher ---------------------------------------------------------------
extern "C" void kernel_launch(void* const* d_in, const int* in_sizes, int n_in,
                              void* d_out, int out_size, void* d_ws, size_t ws_size,
                              hipStream_t stream) {
    const float* x  = (const float*)d_in[0];
    const float* Wq = (const float*)d_in[1];
    const float* Wk = (const float*)d_in[2];
    const float* Wv = (const float*)d_in[3];
    float* out = (float*)d_out;

    bf16* WTfrag = (bf16*)d_ws;

    wt_frag_kernel<<<dim3(384), dim3(256), 0, stream>>>(Wq, Wk, Wv, WTfrag);
    fused_kernel<<<dim3(512), dim3(512), 90112, stream>>>(x, WTfrag, out);
}

// Round 18
// 73.492 us; speedup vs baseline: 1.1024x; 1.1024x over previous
//
#include <hip/hip_runtime.h>
#include <hip/hip_bf16.h>

typedef __bf16 bf16;
typedef __bf16 bf16x8 __attribute__((ext_vector_type(8)));
typedef __bf16 bf16x4 __attribute__((ext_vector_type(4)));
typedef float  f32x4  __attribute__((ext_vector_type(4)));

#define MFMA16(a,b,c) __builtin_amdgcn_mfma_f32_16x16x32_bf16((a),(b),(c),0,0,0)

__device__ __forceinline__ void gld16(const void* g, void* l) {
    __builtin_amdgcn_global_load_lds(
        (const __attribute__((address_space(1))) void*)g,
        (__attribute__((address_space(3))) void*)l, 16, 0, 0);
}

// Problem sizes: B=512, T=256, C=512, H=64
// ws layout: WTfrag [16 KC][12 nf][64 lane][8] bf16 @ 0  (196,608 bytes)

// ---- kernel 0: build pre-fragmented WT --------------------------------------
// WTfrag byte addr (KC*12+nf)*1024 + l*16 holds B-frag: 8 bf16 =
//   W_mat[k = KC*32 + (l>>4)*8 + j][col = (nf&3)*16 + (l&15)],  mat = nf>>2.
__global__ void __launch_bounds__(256) wt_frag_kernel(
        const float* __restrict__ Wq, const float* __restrict__ Wk,
        const float* __restrict__ Wv, bf16* __restrict__ WTfrag) {
    int tid = blockIdx.x * 256 + threadIdx.x;     // 98304 total
    int j  = tid & 7;
    int l  = (tid >> 3) & 63;
    int f  = tid >> 9;            // 0..767 = KC*12 + nf
    int nf = f % 12;
    int KC = f / 12;
    int k   = KC * 32 + (l >> 4) * 8 + j;
    int col = (nf & 3) * 16 + (l & 15);
    const float* W = (nf < 4) ? Wq : ((nf < 8) ? Wk : Wv);
    WTfrag[tid] = (bf16)W[k * 64 + col];
}

// ---- fused kernel: R16 basin + R17-style legal prefetch ---------------------
// grid 512 (block = batch), 256 threads (4 waves), LDS 77824 -> 2 blocks/CU.
// Register model: (256,2) -> 8 waves/CU = 2/SIMD -> 256 regs/wave. R17 proved
// stage-before-compute WITHOUT sched_barrier at this budget does not spill
// (R10/R11's poison = sched_barrier pins + persistent bfr regs; R12-14's =
// 128-cap at 4 waves/SIMD). R16 proved 2 blocks/CU co-residency is worth
// ~10us. This round combines them:
// Phase 1: x DOUBLE-buffered @0/@32768; wt single @65536 (12KB). Per chunk:
//   stage_x(k+1 -> dead buf) [in flight under MFMAs] -> compute(k) ->
//   __syncthreads [read-done + drain] -> stage_wt(k+1) -> __syncthreads.
//   All waits compiler-managed full drains; no manual vmcnt; no sched_barrier.
// Phase 2: K -> @0, V -> @32768 (dead x bufs), swizzled; Q via wave-private
//   Pl @65536+w*2304 (barrier-free, same-wave lgkmcnt ordering).
// Phase 3: causal flash attention (R16 math).
__global__ void __launch_bounds__(256, 2) fused_kernel(
        const float* __restrict__ x, const bf16* __restrict__ WTfrag,
        float* __restrict__ out) {
    extern __shared__ char smem[];

    const int tid = threadIdx.x;
    const int l   = tid & 63;
    const int w   = tid >> 6;
    const int lo  = l & 15;
    const int hi  = l >> 4;
    const int b   = blockIdx.x;
    const char* xb = (const char*)x + (size_t)b * 524288;   // 256 rows * 2048 B
    const char* wb = (const char*)WTfrag;

    // ---------------- phase 1: projection ----------------
    f32x4 acc[4][12];                        // [mq][nf]; 192 regs
    #pragma unroll
    for (int mq = 0; mq < 4; ++mq)
        #pragma unroll
        for (int nf = 0; nf < 12; ++nf)
            acc[mq][nf] = (f32x4){0.f, 0.f, 0.f, 0.f};

    auto stage_x = [&](int buf, int kc) {
        #pragma unroll
        for (int j = 0; j < 8; ++j) {        // 2048 16B-units, 8/thread
            const int s   = j * 256 + tid;
            const int row = s >> 3;
            const int uL  = (s & 7) ^ (row & 7);   // inverse-swizzle on SOURCE
            gld16(xb + (size_t)row * 2048 + kc * 128 + uL * 16,
                  smem + buf * 32768 + s * 16);
        }
    };
    auto stage_wt = [&](int kc) {
        #pragma unroll
        for (int j = 0; j < 3; ++j) {        // 12 KB verbatim, 3/thread
            const int s = j * 256 + tid;
            gld16(wb + kc * 12288 + s * 16, smem + 65536 + s * 16);
        }
    };

    stage_x(0, 0);
    stage_wt(0);
    __syncthreads();                         // chunk 0 landed

    #pragma unroll 1
    for (int kc = 0; kc < 16; ++kc) {
        // (1) prefetch x(k+1) into the dead buffer; lands under compute(k).
        //     (target buf was fully read by compute(k-1); the barrier at the
        //      end of iter k-1 guarantees all waves are done with it.)
        if (kc < 15) stage_x((kc + 1) & 1, kc + 1);
        // (2) compute chunk kc
        const char* xlds = smem + (kc & 1) * 32768;
        bf16x8 a[4];
        #pragma unroll
        for (int mq = 0; mq < 4; ++mq) {
            const int row = mq * 64 + w * 16 + lo;      // row&7 == lo&7
            const int u0  = (hi * 2)     ^ (lo & 7);
            const int u1  = (hi * 2 + 1) ^ (lo & 7);
            f32x4 v0 = *(const f32x4*)(xlds + row * 128 + u0 * 16);
            f32x4 v1 = *(const f32x4*)(xlds + row * 128 + u1 * 16);
            bf16x8 t;
            t[0] = (bf16)v0[0]; t[1] = (bf16)v0[1]; t[2] = (bf16)v0[2]; t[3] = (bf16)v0[3];
            t[4] = (bf16)v1[0]; t[5] = (bf16)v1[1]; t[6] = (bf16)v1[2]; t[7] = (bf16)v1[3];
            a[mq] = t;
        }
        #pragma unroll
        for (int nf = 0; nf < 12; ++nf) {
            bf16x8 bf_ = *(const bf16x8*)(smem + 65536 + nf * 1024 + l * 16);
            #pragma unroll
            for (int mq = 0; mq < 4; ++mq)
                acc[mq][nf] = MFMA16(a[mq], bf_, acc[mq][nf]);
        }
        // (3) read-done for xlds+wt, and drains x(k+1)'s staging
        __syncthreads();
        // (4) refill the single wt buffer (L2-fed, short)
        if (kc < 15) {
            stage_wt(kc + 1);
            __syncthreads();
        }
    }

    // ---------------- phase 2: K,V -> LDS; Q -> regs ----------------
    char* Kb = smem;                         // dead x buf 0
    char* Vb = smem + 32768;                 // dead x buf 1
    #pragma unroll
    for (int nf = 4; nf < 12; ++nf) {
        #pragma unroll
        for (int mq = 0; mq < 4; ++mq) {
            if (nf < 8) {
                #pragma unroll
                for (int i = 0; i < 4; ++i) {      // K: row varies with i
                    bf16 v = (bf16)acc[mq][nf][i];
                    const int row = mq * 64 + w * 16 + hi * 4 + i;
                    const int col = (nf - 4) * 16 + lo;
                    const int u   = col >> 3;
                    *(bf16*)(Kb + row * 128 + ((u ^ (row & 7)) << 4) +
                             (col & 7) * 2) = v;
                }
            } else {
                // V: 4 consecutive t in one 16B unit -> single 8B store
                const int h  = (nf - 8) * 16 + lo;
                const int tb = mq * 64 + w * 16 + hi * 4;   // tb&7 in {0,4}
                const int u  = tb >> 3;
                bf16x4 pk;
                pk[0] = (bf16)acc[mq][nf][0]; pk[1] = (bf16)acc[mq][nf][1];
                pk[2] = (bf16)acc[mq][nf][2]; pk[3] = (bf16)acc[mq][nf][3];
                *(bf16x4*)(Vb + h * 512 + ((u ^ (h & 7)) << 4) +
                           (tb & 7) * 2) = pk;
            }
        }
    }

    // Q: acc[qf][0..3] -> qfr via wave-private Pl (barrier-free; same-wave
    // ds_write->ds_read ordered by compiler lgkmcnt)
    bf16* Pl = (bf16*)(smem + 65536) + w * 1152;
    bf16x8 qfr[4][2];
    #pragma unroll
    for (int qf = 0; qf < 4; ++qf) {
        #pragma unroll
        for (int nf = 0; nf < 4; ++nf)
            #pragma unroll
            for (int i = 0; i < 4; ++i)
                Pl[(hi * 4 + i) * 72 + nf * 16 + lo] = (bf16)acc[qf][nf][i];
        #pragma unroll
        for (int ks = 0; ks < 2; ++ks)
            qfr[qf][ks] = *(const bf16x8*)(Pl + lo * 72 + ks * 32 + hi * 8);
    }
    __syncthreads();        // K/V scatter visible to all waves before phase 3

    // ---------------- phase 3: causal flash attention ----------------
    f32x4 o[4][4];
    #pragma unroll
    for (int qf = 0; qf < 4; ++qf)
        #pragma unroll
        for (int mf = 0; mf < 4; ++mf)
            o[qf][mf] = (f32x4){0.f, 0.f, 0.f, 0.f};
    float m2[4]   = {-INFINITY, -INFINITY, -INFINITY, -INFINITY};
    float lsum[4] = {0.f, 0.f, 0.f, 0.f};

    const float SC = 0.125f * 1.44269504088896340736f;  // scale * log2(e)

    #pragma unroll
    for (int kc = 0; kc < 4; ++kc) {
        bf16x8 vf[4][2];
        #pragma unroll
        for (int mf = 0; mf < 4; ++mf)
            #pragma unroll
            for (int ks = 0; ks < 2; ++ks) {
                const int h = mf * 16 + lo;             // h&7 == lo&7
                const int u = kc * 8 + ks * 4 + hi;
                vf[mf][ks] = *(const bf16x8*)(Vb + h * 512 + ((u ^ (lo & 7)) << 4));
            }

        #pragma unroll
        for (int qf = kc; qf < 4; ++qf) {
            f32x4 s[4];
            #pragma unroll
            for (int kf = 0; kf < 4; ++kf) {
                const int key = kc * 64 + kf * 16 + lo; // key&7 == lo&7
                bf16x8 k0 = *(const bf16x8*)(Kb + key * 128 + ((hi ^ (lo & 7)) << 4));
                bf16x8 k1 = *(const bf16x8*)(Kb + key * 128 + (((4 + hi) ^ (lo & 7)) << 4));
                f32x4 t = (f32x4){0.f, 0.f, 0.f, 0.f};
                t = MFMA16(k0, qfr[qf][0], t);
                t = MFMA16(k1, qfr[qf][1], t);
                s[kf] = t;
            }
            float mx = -INFINITY;
            #pragma unroll
            for (int kf = 0; kf < 4; ++kf)
                #pragma unroll
                for (int i = 0; i < 4; ++i) {
                    float v = s[kf][i] * SC;
                    if (kc == qf && (kf * 16 + hi * 4 + i) > (w * 16 + lo)) v = -INFINITY;
                    s[kf][i] = v;
                    mx = fmaxf(mx, v);
                }
            mx = fmaxf(mx, __shfl_xor(mx, 16));
            mx = fmaxf(mx, __shfl_xor(mx, 32));
            const float mnew = fmaxf(m2[qf], mx);
            const float rsc  = exp2f(m2[qf] - mnew);
            m2[qf] = mnew;

            float cs = 0.f;
            bf16x4 pk[4];
            #pragma unroll
            for (int kf = 0; kf < 4; ++kf)
                #pragma unroll
                for (int i = 0; i < 4; ++i) {
                    float p = exp2f(s[kf][i] - mnew);
                    cs += p;
                    pk[kf][i] = (bf16)p;
                }
            cs += __shfl_xor(cs, 16);
            cs += __shfl_xor(cs, 32);
            lsum[qf] = lsum[qf] * rsc + cs;

            #pragma unroll
            for (int kf = 0; kf < 4; ++kf)
                *(bf16x4*)(Pl + lo * 72 + kf * 16 + hi * 4) = pk[kf];

            #pragma unroll
            for (int mf = 0; mf < 4; ++mf) {
                o[qf][mf][0] *= rsc; o[qf][mf][1] *= rsc;
                o[qf][mf][2] *= rsc; o[qf][mf][3] *= rsc;
            }
            #pragma unroll
            for (int ks = 0; ks < 2; ++ks) {
                bf16x8 pf = *(const bf16x8*)(Pl + lo * 72 + ks * 32 + hi * 8);
                #pragma unroll
                for (int mf = 0; mf < 4; ++mf)
                    o[qf][mf] = MFMA16(vf[mf][ks], pf, o[qf][mf]);
            }
        }
    }

    // epilogue: out[b][q][h] fp32, coalesced f32x4
    #pragma unroll
    for (int qf = 0; qf < 4; ++qf) {
        const float inv = 1.0f / lsum[qf];
        const int q = qf * 64 + w * 16 + lo;
        #pragma unroll
        for (int mf = 0; mf < 4; ++mf) {
            f32x4 r4;
            r4[0] = o[qf][mf][0] * inv; r4[1] = o[qf][mf][1] * inv;
            r4[2] = o[qf][mf][2] * inv; r4[3] = o[qf][mf][3] * inv;
            *(f32x4*)(out + (b * 256 + q) * 64 + mf * 16 + hi * 4) = r4;
        }
    }
}

// ---- launcher ---------------------------------------------------------------
extern "C" void kernel_launch(void* const* d_in, const int* in_sizes, int n_in,
                              void* d_out, int out_size, void* d_ws, size_t ws_size,
                              hipStream_t stream) {
    const float* x  = (const float*)d_in[0];
    const float* Wq = (const float*)d_in[1];
    const float* Wk = (const float*)d_in[2];
    const float* Wv = (const float*)d_in[3];
    float* out = (float*)d_out;

    bf16* WTfrag = (bf16*)d_ws;

    wt_frag_kernel<<<dim3(384), dim3(256), 0, stream>>>(Wq, Wk, Wv, WTfrag);
    fused_kernel<<<dim3(512), dim3(256), 77824, stream>>>(x, WTfrag, out);
}